// Round 1
// 95.939 us; speedup vs baseline: 1.0674x; 1.0674x over previous
//
#include <hip/hip_runtime.h>
#include <hip/hip_bf16.h>

// NT-Xent with more negatives: N=2048, D=128, k=4 augs.
// sim = norm(z[4096,128]) @ norm(z_all[8192,128])^T * 2   (T=0.5)
// loss = mean_rows( logsumexp(masked sim) - pos )
// R11: Bn (2 MB) is L2-resident -> LDS staging was pure overhead (guide
// Common-mistake #7). kgemm v2 reads MFMA fragments DIRECTLY from global
// (16 rows x 64B per dwordx4 load, line-coalesced), no LDS, no main-loop
// barriers. 8 waves/block, wave = 64 rows x 16 cols (A hoisted: a[4][4],
// 64 VGPR), B redundancy 1x/block -> ~192 MB L2 traffic (~5.6K cyc/CU)
// under the MFMA floor (~9.9K). Grid (64,8) x 512thr = 2 blocks/CU =
// 4 waves/SIMD. kfin re-gridded 32->256 blocks (serial depth 32->4 rows).
// Epilogue exp fused to exp2(fma(x, 2log2e, -2log2e)).

#define NN      2048
#define DD      128
#define TWO_N   4096
#define FOUR_N  8192
#define CTG     8      // col groups (8192 / 1024)
#define C2L2E   2.8853900817779268f   // 2*log2(e): exp(2s-2)=exp2(fma(s,C,-C))

using frag_ab = __attribute__((ext_vector_type(8))) short;  // 8 bf16 = 16 B
using f32x4   = __attribute__((ext_vector_type(4))) float;

// ---------------- Kernel 1: L2-normalize rows -> bf16; zero out ----------
__global__ __launch_bounds__(256) void knorm(const float* __restrict__ p0,
                                             const float* __restrict__ p1,
                                             const float* __restrict__ p2,
                                             const float* __restrict__ p3,
                                             short* __restrict__ Bn,
                                             float* __restrict__ out) {
  if (blockIdx.x == 0 && threadIdx.x == 0) out[0] = 0.0f;
  int wave = threadIdx.x >> 6, lane = threadIdx.x & 63;
  int row = blockIdx.x * 4 + wave;                 // 0..8191
  int q = row >> 11, idx = row & (NN - 1);
  const float* src = (q == 0) ? p0 : (q == 1) ? p1 : (q == 2) ? p2 : p3;
  const float2* s2 = (const float2*)(src + (size_t)idx * DD);
  float2 v = s2[lane];
  float ss = v.x * v.x + v.y * v.y;
  #pragma unroll
  for (int sh = 1; sh < 64; sh <<= 1) ss += __shfl_xor(ss, sh, 64);
  float inv = 1.0f / fmaxf(sqrtf(ss), 1e-8f);
  __hip_bfloat162 o;
  o.x = __float2bfloat16(v.x * inv);
  o.y = __float2bfloat16(v.y * inv);
  ((__hip_bfloat162*)(Bn + (size_t)row * DD))[lane] = o;
}

// ---------------- Kernel 2: LDS-free GEMM + partial sumexp ----------------
// Grid (64, 8) = 512 blocks, 512 threads = 8 waves; 2 blocks/CU, 4 waves/SIMD.
// Block: 64 A-rows x 1024 B-cols (8 tiles of 128 cols). Wave w: all 64 rows,
// cols w*16..w*16+16 of each tile. Fragments loaded straight from global
// (L2-resident): frag(row r_, chunk k*4+quad) = Bn[r_*128 + (k*4+quad)*8].
// pS[row][by] = sum_{cols in group} exp(2*sim - 2).
__global__ __launch_bounds__(512, 4) void kgemm(const short* __restrict__ Bn,
                                                float* __restrict__ pS) {
  __shared__ float sS[64][CTG + 1];   // +1 pad vs 4-quad same-bank writes

  int t = threadIdx.x, wave = t >> 6, lane = t & 63;
  int quad = lane >> 4, l16 = lane & 15;
  int bx = blockIdx.x, by = blockIdx.y;

  // Hoist A fragments: rows bx*64 + rf*16 + l16, 16B chunk (k*4+quad).
  const short* gA = Bn + (size_t)(bx * 64 + l16) * DD + quad * 8;
  frag_ab a[4][4];                                  // [k][rf], 64 VGPR
  #pragma unroll
  for (int rf = 0; rf < 4; ++rf)
    #pragma unroll
    for (int k = 0; k < 4; ++k)
      a[k][rf] = *(const frag_ab*)(gA + (size_t)rf * 16 * DD + k * 32);

  // B base: col (sim-space) = by*1024 + g*128 + wave*16 + l16.
  const short* gB = Bn + (size_t)(by * 1024 + wave * 16 + l16) * DD + quad * 8;

  float sAcc[4][4];
  #pragma unroll
  for (int rf = 0; rf < 4; ++rf)
    #pragma unroll
    for (int r = 0; r < 4; ++r) sAcc[rf][r] = 0.f;

  #pragma unroll 1
  for (int g = 0; g < 8; ++g) {
    const short* gBg = gB + (size_t)g * 128 * DD;
    frag_ab bb[4];
    #pragma unroll
    for (int k = 0; k < 4; ++k)
      bb[k] = *(const frag_ab*)(gBg + k * 32);

    f32x4 acc[4];
    #pragma unroll
    for (int rf = 0; rf < 4; ++rf) acc[rf] = (f32x4){0.f, 0.f, 0.f, 0.f};
    #pragma unroll
    for (int k = 0; k < 4; ++k)
      #pragma unroll
      for (int rf = 0; rf < 4; ++rf)
        acc[rf] = __builtin_amdgcn_mfma_f32_16x16x32_bf16(a[k][rf], bb[k], acc[rf], 0, 0, 0);

    // Register epilogue: exp(2*sim-2) = exp2(fma(sim, 2log2e, -2log2e)).
    #pragma unroll
    for (int rf = 0; rf < 4; ++rf)
      #pragma unroll
      for (int r = 0; r < 4; ++r)
        sAcc[rf][r] += __builtin_amdgcn_exp2f(fmaf(acc[rf][r], C2L2E, -C2L2E));
  }

  // Fold 16 cols (l16 lanes) -> per-row partial per wave(=col group).
  #pragma unroll
  for (int rf = 0; rf < 4; ++rf)
    #pragma unroll
    for (int r = 0; r < 4; ++r) {
      float s = sAcc[rf][r];
      s += __shfl_xor(s, 1, 64);
      s += __shfl_xor(s, 2, 64);
      s += __shfl_xor(s, 4, 64);
      s += __shfl_xor(s, 8, 64);
      if (l16 == 0) sS[rf * 16 + quad * 4 + r][wave] = s;
    }
  __syncthreads();
  if (t < 64) {
    const float* row = sS[t];
    pS[(size_t)(bx * 64 + t) * CTG + by] =
        ((row[0] + row[1]) + (row[2] + row[3])) +
        ((row[4] + row[5]) + (row[6] + row[7]));
  }
}

// ---------------- Kernel 3: finisher (256 blocks x 256 thr) ---------------
// Block b handles rows [b*16, b*16+16): merge 8 group-partials, subtract
// the 3 masked diagonal exps (self, aug3-diag, aug4-diag), add pos term,
// block-reduce, one atomicAdd into out. Serial depth 4 rows/wave (was 32).
__global__ __launch_bounds__(256) void kfin(const short* __restrict__ Bn,
                                            const float* __restrict__ pS,
                                            float* __restrict__ out) {
  int t = threadIdx.x, wave = t >> 6, lane = t & 63;
  int grBase = blockIdx.x * 16;
  __shared__ float sRed[4];

  float wloss = 0.f;                                // valid on lane 0
  #pragma unroll 1
  for (int rr = wave; rr < 16; rr += 4) {           // 4 rows per wave
    int gr = grBase + rr;
    int idx = gr & (NN - 1), half = gr >> 11;
    float S = (lane < CTG) ? pS[(size_t)gr * CTG + lane] : 0.f;
    #pragma unroll
    for (int sh = 1; sh < 8; sh <<= 1) S += __shfl_xor(S, sh, 64);
    // dots vs: self (gr), pos ((1-half)*NN+idx), aug3 (4096+idx), aug4 (6144+idx)
    unsigned int ua = ((const unsigned int*)(Bn + (size_t)gr * DD))[lane];
    unsigned int ub = ((const unsigned int*)(Bn + (size_t)((1 - half) * NN + idx) * DD))[lane];
    unsigned int uc = ((const unsigned int*)(Bn + (size_t)(2 * NN + idx) * DD))[lane];
    unsigned int ud = ((const unsigned int*)(Bn + (size_t)(3 * NN + idx) * DD))[lane];
    float a0 = __uint_as_float((ua & 0xffffu) << 16), a1 = __uint_as_float(ua & 0xffff0000u);
    float b0 = __uint_as_float((ub & 0xffffu) << 16), b1 = __uint_as_float(ub & 0xffff0000u);
    float c0 = __uint_as_float((uc & 0xffffu) << 16), c1 = __uint_as_float(uc & 0xffff0000u);
    float d0 = __uint_as_float((ud & 0xffffu) << 16), d1 = __uint_as_float(ud & 0xffff0000u);
    float daa = a0 * a0 + a1 * a1;
    float dab = a0 * b0 + a1 * b1;
    float dac = a0 * c0 + a1 * c1;
    float dad = a0 * d0 + a1 * d1;
    #pragma unroll
    for (int sh = 1; sh < 64; sh <<= 1) {
      daa += __shfl_xor(daa, sh, 64);
      dab += __shfl_xor(dab, sh, 64);
      dac += __shfl_xor(dac, sh, 64);
      dad += __shfl_xor(dad, sh, 64);
    }
    // subtract masked diagonals: self + aug3 + aug4 (pos block stays)
    float Sc = S - __expf(fmaf(daa, 2.0f, -2.0f))
                 - __expf(fmaf(dac, 2.0f, -2.0f))
                 - __expf(fmaf(dad, 2.0f, -2.0f));
    float loss = (2.0f + __logf(Sc)) - 2.0f * dab;
    if (lane == 0) wloss += loss;
  }
  if (lane == 0) sRed[wave] = wloss;
  __syncthreads();
  if (t == 0)
    atomicAdd(out, (sRed[0] + sRed[1] + sRed[2] + sRed[3]) * (1.0f / (float)TWO_N));
}

extern "C" void kernel_launch(void* const* d_in, const int* in_sizes, int n_in,
                              void* d_out, int out_size, void* d_ws, size_t ws_size,
                              hipStream_t stream) {
  (void)in_sizes; (void)n_in; (void)out_size; (void)ws_size;
  const float* p0 = (const float*)d_in[0];
  const float* p1 = (const float*)d_in[1];
  const float* p2 = (const float*)d_in[2];
  const float* p3 = (const float*)d_in[3];

  // ws layout: Bn bf16 [8192][128] (2 MB) | pS f32 [4096][8] (128 KB)
  short* Bn = (short*)d_ws;
  float* pS = (float*)((char*)d_ws + (size_t)FOUR_N * DD * sizeof(short));
  float* out = (float*)d_out;

  knorm<<<FOUR_N / 4, 256, 0, stream>>>(p0, p1, p2, p3, Bn, out);
  kgemm<<<dim3(TWO_N / 64, CTG), 512, 0, stream>>>(Bn, pS);
  kfin<<<TWO_N / 16, 256, 0, stream>>>(Bn, pS, out);
}